// Round 1
// baseline (584.990 us; speedup 1.0000x reference)
//
#include <hip/hip_runtime.h>
#include <hip/hip_bf16.h>
#include <stdint.h>

// Encoder pipeline, all activations token-major [T=32768, C] bf16.
//   im2col (K=192 padded) -> convGEMM(+b0,prelu a0) -> 3x { GEMM(+b) -> colstats
//   -> bnfold -> bnact(prelu) } -> mixprep(+pos, prelu am) -> mixGEMM(+bm, fp32)
//   -> permutation row-gather.
// ws usage (~136 MB): B0(64MB) | B1(64MB) | part(512KB) | scsh(8KB) | bf16 weights(~7.7MB)

typedef __attribute__((ext_vector_type(8))) short bf16x8;
typedef __attribute__((ext_vector_type(4))) float f32x4;

__device__ __forceinline__ float bf2f(uint32_t u) {
  union { uint32_t i; float f; } v; v.i = u << 16; return v.f;
}
__device__ __forceinline__ ushort f2bf(float f) {
  union { float f; uint32_t i; } v; v.f = f;
  uint32_t i = v.i;
  return (ushort)((i + 0x7FFFu + ((i >> 16) & 1u)) >> 16);
}

// ---------------------------------------------------------------- GEMM
// Out[t,d] = sum_k A[t,k] * Bw[d,k]  (both bf16, K-contiguous), fp32 accum.
// 128x128 tile, BK=64, 4 waves (2x2 of 64x64), mfma_f32_16x16x32_bf16.
// LDS tiles [128][64] bf16 K-major, XOR chunk swizzle (slot = chunk ^ (row&7)):
// staged via global_load_lds with inverse-swizzled global source (rule #21).
// EPI: 0 = bias+prelu(alpha) -> bf16 ; 1 = bias -> bf16 ; 2 = bias -> fp32
template<int EPI>
__global__ void __launch_bounds__(256)
gemm_kernel(const ushort* __restrict__ A, const ushort* __restrict__ Bw,
            const float* __restrict__ bias, const float* __restrict__ alpha,
            void* __restrict__ outp, int K, int Dout)
{
  __shared__ __align__(16) ushort At[128 * 64];
  __shared__ __align__(16) ushort Bt[128 * 64];
  const int tid  = threadIdx.x;
  const int lane = tid & 63;
  const int wid  = tid >> 6;
  const int wm = wid >> 1, wn = wid & 1;
  const int t0 = blockIdx.y << 7;
  const int d0 = blockIdx.x << 7;

  f32x4 acc[4][4] = {};

  const int srow   = lane >> 3;   // 0..7 row within an 8-row staging group
  const int schunk = lane & 7;    // 16B slot within a 128B row

  for (int k0 = 0; k0 < K; k0 += 64) {
    // stage: wave wid covers rows [wid*32, wid*32+32) of each tile
#pragma unroll
    for (int i = 0; i < 4; ++i) {
      int rbase = (wid << 5) + (i << 3);
      int r = rbase + srow;
      int ca = schunk ^ (r & 7);  // inverse swizzle on the global source
      const ushort* ga = A  + (size_t)(t0 + r) * K + k0 + (ca << 3);
      __builtin_amdgcn_global_load_lds(
          (const __attribute__((address_space(1))) uint32_t*)ga,
          (__attribute__((address_space(3))) uint32_t*)(&At[rbase << 6]), 16, 0, 0);
      const ushort* gb = Bw + (size_t)(d0 + r) * K + k0 + (ca << 3);
      __builtin_amdgcn_global_load_lds(
          (const __attribute__((address_space(1))) uint32_t*)gb,
          (__attribute__((address_space(3))) uint32_t*)(&Bt[rbase << 6]), 16, 0, 0);
    }
    __syncthreads();

#pragma unroll
    for (int kk = 0; kk < 2; ++kk) {
      bf16x8 af[4], bfr[4];
      const int kc = (kk << 2) + (lane >> 4);   // 16B chunk index 0..7
#pragma unroll
      for (int m = 0; m < 4; ++m) {
        int row = (wm << 6) + (m << 4) + (lane & 15);
        af[m]  = *(const bf16x8*)&At[(row << 6) + ((kc ^ (row & 7)) << 3)];
        int col = (wn << 6) + (m << 4) + (lane & 15);
        bfr[m] = *(const bf16x8*)&Bt[(col << 6) + ((kc ^ (col & 7)) << 3)];
      }
#pragma unroll
      for (int m = 0; m < 4; ++m)
#pragma unroll
        for (int n = 0; n < 4; ++n)
          acc[m][n] = __builtin_amdgcn_mfma_f32_16x16x32_bf16(af[m], bfr[n], acc[m][n], 0, 0, 0);
    }
    __syncthreads();
  }

  // epilogue: C/D layout col = lane&15, row = (lane>>4)*4 + reg
  float a0 = (EPI == 0) ? alpha[0] : 0.0f;
#pragma unroll
  for (int n = 0; n < 4; ++n) {
    int d = d0 + (wn << 6) + (n << 4) + (lane & 15);
    float bs = bias[d];
#pragma unroll
    for (int m = 0; m < 4; ++m) {
      int tb = t0 + (wm << 6) + (m << 4) + ((lane >> 4) << 2);
#pragma unroll
      for (int r = 0; r < 4; ++r) {
        float v = acc[m][n][r] + bs;
        if (EPI == 0) v = v > 0.f ? v : a0 * v;
        if (EPI == 2) ((float*)outp)[(size_t)(tb + r) * Dout + d] = v;
        else          ((ushort*)outp)[(size_t)(tb + r) * Dout + d] = f2bf(v);
      }
    }
  }
}

// ------------------------------------------------------- BN column stats
// Y [32768, 1024] bf16 -> per-(block row-slab) partial sum/sumsq, deterministic.
__global__ void colstats_kernel(const ushort* __restrict__ Y, float* __restrict__ part) {
  int d  = (blockIdx.x << 8) + threadIdx.x;   // grid.x = 4
  int t0 = blockIdx.y << 9;                   // grid.y = 64 (512 rows each)
  float s = 0.f, s2 = 0.f;
  const ushort* p = Y + (size_t)t0 * 1024 + d;
  for (int t = 0; t < 512; ++t) {
    float v = bf2f((uint32_t)p[(size_t)t * 1024]);
    s += v; s2 += v * v;
  }
  float* pr = part + (size_t)blockIdx.y * 2048;
  pr[d] = s; pr[1024 + d] = s2;
}

__global__ void bnfold_kernel(const float* __restrict__ part, const float* __restrict__ g,
                              const float* __restrict__ bt, float* __restrict__ scsh) {
  int d = (blockIdx.x << 8) + threadIdx.x;    // grid 4
  float s = 0.f, s2 = 0.f;
  for (int j = 0; j < 64; ++j) { s += part[j * 2048 + d]; s2 += part[j * 2048 + 1024 + d]; }
  float mean = s * (1.f / 32768.f);
  float var  = s2 * (1.f / 32768.f) - mean * mean;
  float sc = g[d] * rsqrtf(var + 1e-5f);
  scsh[d] = sc;
  scsh[1024 + d] = bt[d] - mean * sc;
}

// y = prelu(y*sc + sh, p), in place, 8 bf16 per thread (16B loads/stores)
__global__ void bnact_kernel(ushort* __restrict__ Y, const float* __restrict__ scsh,
                             const float* __restrict__ p) {
  size_t i = (((size_t)blockIdx.x << 8) + threadIdx.x) << 3;
  int d = (int)(i & 1023);
  float pp = p[0];
  uint4 raw = *(const uint4*)(Y + i);
  uint32_t w[4] = {raw.x, raw.y, raw.z, raw.w};
  uint32_t o[4];
#pragma unroll
  for (int q = 0; q < 4; ++q) {
    int dd = d + q * 2;
    float v0 = bf2f(w[q] & 0xFFFFu) * scsh[dd]     + scsh[1024 + dd];
    float v1 = bf2f(w[q] >> 16)     * scsh[dd + 1] + scsh[1024 + dd + 1];
    v0 = v0 > 0.f ? v0 : pp * v0;
    v1 = v1 > 0.f ? v1 : pp * v1;
    o[q] = (uint32_t)f2bf(v0) | ((uint32_t)f2bf(v1) << 16);
  }
  *(uint4*)(Y + i) = make_uint4(o[0], o[1], o[2], o[3]);
}

// enc = prelu(act3 + pos[t%256], am), in place
__global__ void mixprep_kernel(ushort* __restrict__ A3, const float* __restrict__ pos,
                               const float* __restrict__ am) {
  size_t i = (((size_t)blockIdx.x << 8) + threadIdx.x) << 3;
  int c  = (int)(i & 1023);
  int pp = (int)((i >> 10) & 255);
  float aa = am[0];
  uint4 raw = *(const uint4*)(A3 + i);
  const float4* pb = (const float4*)(pos + ((size_t)pp << 10) + c);
  float4 pA = pb[0], pB = pb[1];
  float pv[8] = {pA.x, pA.y, pA.z, pA.w, pB.x, pB.y, pB.z, pB.w};
  uint32_t w[4] = {raw.x, raw.y, raw.z, raw.w};
  uint32_t o[4];
#pragma unroll
  for (int q = 0; q < 4; ++q) {
    float v0 = bf2f(w[q] & 0xFFFFu) + pv[2 * q];
    float v1 = bf2f(w[q] >> 16)     + pv[2 * q + 1];
    v0 = v0 > 0.f ? v0 : aa * v0;
    v1 = v1 > 0.f ? v1 : aa * v1;
    o[q] = (uint32_t)f2bf(v0) | ((uint32_t)f2bf(v1) << 16);
  }
  *(uint4*)(A3 + i) = make_uint4(o[0], o[1], o[2], o[3]);
}

// out[b,i,:] = mix[b, perm[b,i], :]  (2KB coalesced rows)
__global__ void gather_kernel(const float* __restrict__ mix, const int* __restrict__ perm,
                              float* __restrict__ out) {
  int row = blockIdx.x;                 // 32768
  int b = row >> 8;
  int src = (b << 8) + perm[row];
  float4 v = ((const float4*)(mix + ((size_t)src << 9)))[threadIdx.x];   // 128 thr x 16B
  ((float4*)(out + ((size_t)row << 9)))[threadIdx.x] = v;
}

// ----------------------------------------------------------- preprocessing
__global__ void f2b_kernel(const float* __restrict__ in, ushort* __restrict__ out, int n) {
  int i = (blockIdx.x << 8) + threadIdx.x;
  if (i < n) out[i] = f2bf(in[i]);
}

__global__ void padw0_kernel(const float* __restrict__ w0, ushort* __restrict__ o) {
  int d = blockIdx.x, j = threadIdx.x;  // 1024 x 192
  o[d * 192 + j] = (j < 147) ? f2bf(w0[d * 147 + j]) : (ushort)0;
}

// patch im2col: P[t=b*256+pi*16+pj][j=cin*49+dy*7+dx] = x[b,cin,7pi+dy,7pj+dx]
__global__ void im2col_kernel(const float* __restrict__ x, ushort* __restrict__ P) {
  int t = blockIdx.x;        // 32768
  int j = threadIdx.x;       // 192
  ushort v = 0;
  if (j < 147) {
    int b = t >> 8, pidx = t & 255;
    int pi = pidx >> 4, pj = pidx & 15;
    int cin = j / 49, rem = j - cin * 49;
    int dy = rem / 7, dx = rem - dy * 7;
    v = f2bf(x[(size_t)(b * 3 + cin) * 12544 + (size_t)(pi * 7 + dy) * 112 + (pj * 7 + dx)]);
  }
  P[(size_t)t * 192 + j] = v;
}

extern "C" void kernel_launch(void* const* d_in, const int* in_sizes, int n_in,
                              void* d_out, int out_size, void* d_ws, size_t ws_size,
                              hipStream_t stream) {
  const float* x   = (const float*)d_in[0];
  const float* w0  = (const float*)d_in[1];
  const float* b0  = (const float*)d_in[2];
  const float* a0  = (const float*)d_in[3];
  const float* w1  = (const float*)d_in[4];
  const float* b1  = (const float*)d_in[5];
  const float* g1  = (const float*)d_in[6];
  const float* bt1 = (const float*)d_in[7];
  const float* p1  = (const float*)d_in[8];
  const float* w2  = (const float*)d_in[9];
  const float* b2  = (const float*)d_in[10];
  const float* g2  = (const float*)d_in[11];
  const float* bt2 = (const float*)d_in[12];
  const float* p2  = (const float*)d_in[13];
  const float* w3  = (const float*)d_in[14];
  const float* b3  = (const float*)d_in[15];
  const float* g3  = (const float*)d_in[16];
  const float* bt3 = (const float*)d_in[17];
  const float* p3  = (const float*)d_in[18];
  const float* pos = (const float*)d_in[19];
  const float* am  = (const float*)d_in[20];
  const float* wm  = (const float*)d_in[21];
  const float* bm  = (const float*)d_in[22];
  const int*  perm = (const int*)d_in[23];

  char* ws = (char*)d_ws;
  ushort* B0   = (ushort*)ws;                                   // 67108864 B
  ushort* B1   = (ushort*)(ws + 67108864);                      // 67108864 B
  float*  part = (float*)(ws + 134217728);                      // 64*2048*4 = 512 KB
  float*  scsh = (float*)(ws + 134217728 + 524288);             // 8 KB
  ushort* w1b  = (ushort*)(ws + 134217728 + 524288 + 8192);
  ushort* w2b  = w1b + 1048576;
  ushort* w3b  = w2b + 1048576;
  ushort* wmb  = w3b + 1048576;
  ushort* w0b  = wmb + 524288;                                  // 1024*192

  // weight conversion to bf16
  f2b_kernel<<<dim3(4096), dim3(256), 0, stream>>>(w1, w1b, 1048576);
  f2b_kernel<<<dim3(4096), dim3(256), 0, stream>>>(w2, w2b, 1048576);
  f2b_kernel<<<dim3(4096), dim3(256), 0, stream>>>(w3, w3b, 1048576);
  f2b_kernel<<<dim3(2048), dim3(256), 0, stream>>>(wm, wmb, 524288);
  padw0_kernel<<<dim3(1024), dim3(192), 0, stream>>>(w0, w0b);
  im2col_kernel<<<dim3(32768), dim3(192), 0, stream>>>(x, B1);

  // patch-embed conv as GEMM: P(B1) x w0b^T -> act0(B0), bias+prelu
  gemm_kernel<0><<<dim3(8, 256), dim3(256), 0, stream>>>(B1, w0b, b0, a0, (void*)B0, 192, 1024);

  // layer 1: B0 -> B1
  gemm_kernel<1><<<dim3(8, 256), dim3(256), 0, stream>>>(B0, w1b, b1, nullptr, (void*)B1, 1024, 1024);
  colstats_kernel<<<dim3(4, 64), dim3(256), 0, stream>>>(B1, part);
  bnfold_kernel<<<dim3(4), dim3(256), 0, stream>>>(part, g1, bt1, scsh);
  bnact_kernel<<<dim3(16384), dim3(256), 0, stream>>>(B1, scsh, p1);

  // layer 2: B1 -> B0
  gemm_kernel<1><<<dim3(8, 256), dim3(256), 0, stream>>>(B1, w2b, b2, nullptr, (void*)B0, 1024, 1024);
  colstats_kernel<<<dim3(4, 64), dim3(256), 0, stream>>>(B0, part);
  bnfold_kernel<<<dim3(4), dim3(256), 0, stream>>>(part, g2, bt2, scsh);
  bnact_kernel<<<dim3(16384), dim3(256), 0, stream>>>(B0, scsh, p2);

  // layer 3: B0 -> B1
  gemm_kernel<1><<<dim3(8, 256), dim3(256), 0, stream>>>(B0, w3b, b3, nullptr, (void*)B1, 1024, 1024);
  colstats_kernel<<<dim3(4, 64), dim3(256), 0, stream>>>(B1, part);
  bnfold_kernel<<<dim3(4), dim3(256), 0, stream>>>(part, g3, bt3, scsh);
  bnact_kernel<<<dim3(16384), dim3(256), 0, stream>>>(B1, scsh, p3);

  // mixer: enc = prelu(act3 + pos, am); out = enc @ wm^T + bm (fp32)
  mixprep_kernel<<<dim3(16384), dim3(256), 0, stream>>>(B1, pos, am);
  gemm_kernel<2><<<dim3(4, 256), dim3(256), 0, stream>>>(B1, wmb, bm, nullptr, (void*)B0, 1024, 512);

  // per-sample token permutation
  gather_kernel<<<dim3(32768), dim3(128), 0, stream>>>((const float*)B0, perm, (float*)d_out);
}

// Round 2
// 489.569 us; speedup vs baseline: 1.1949x; 1.1949x over previous
//
#include <hip/hip_runtime.h>
#include <hip/hip_bf16.h>
#include <stdint.h>

// Encoder pipeline, activations token-major [T=32768, C] bf16.
// im2col -> convGEMM(+b0,prelu) -> 3x { GEMM(+b, fused col-stats) -> bnfold ->
// bnact(prelu[, +pos,prelu am on layer3]) } -> mixGEMM(+bm, fp32, fused perm-scatter)
// ws: B0(64MB) | B1(64MB) | part(2MB) | scsh(8KB) | inv(128KB) | wbuf(2MB)

typedef __attribute__((ext_vector_type(8))) short bf16x8;
typedef __attribute__((ext_vector_type(4))) float f32x4;

__device__ __forceinline__ float bf2f(uint32_t u) {
  union { uint32_t i; float f; } v; v.i = u << 16; return v.f;
}
__device__ __forceinline__ ushort f2bf(float f) {
  union { float f; uint32_t i; } v; v.f = f;
  uint32_t i = v.i;
  return (ushort)((i + 0x7FFFu + ((i >> 16) & 1u)) >> 16);
}

// ---------------------------------------------------------------- GEMM
// Out[t,d] = sum_k A[t,k] * Bw[d,k]  (bf16, K-contiguous), fp32 accum.
// 128x128 tile, BK=64, 4 waves (2x2 of 64x64), mfma_f32_16x16x32_bf16.
// LDS [128][64] K-major, XOR chunk swizzle; staged via global_load_lds with
// inverse-swizzled global source.
// 1-D grid with XCD-grouping swizzle: slot s -> xcd k=s&7; the NX blocks
// sharing an A-tile (same y) run consecutively on one XCD -> A fetched once.
// EPI: 0 = bias+prelu -> bf16
//      1 = bias -> bf16, + per-y-slab column sum/sumsq partials into `part`
//      2 = bias -> fp32, rows scattered via inverse permutation (mixer)
template<int EPI, int XB>
__global__ void __launch_bounds__(256)
gemm_kernel(const ushort* __restrict__ A, const ushort* __restrict__ Bw,
            const float* __restrict__ bias, const float* __restrict__ alpha,
            void* __restrict__ outp, float* __restrict__ part,
            const int* __restrict__ inv, int K, int Dout)
{
  __shared__ __align__(16) ushort At[128 * 64];
  __shared__ __align__(16) ushort Bt[128 * 64];
  const int tid  = threadIdx.x;
  const int lane = tid & 63;
  const int wid  = tid >> 6;
  const int wm = wid >> 1, wn = wid & 1;

  // XCD-grouping swizzle: s = ((y>>3)*NX + x)*8 + (y&7)
  const int s = blockIdx.x;
  const int j = s >> 3;
  const int x = j & ((1 << XB) - 1);
  const int y = ((j >> XB) << 3) | (s & 7);
  const int t0 = y << 7;
  const int d0 = x << 7;

  f32x4 acc[4][4] = {};

  const int srow   = lane >> 3;   // row within an 8-row staging group
  const int schunk = lane & 7;    // 16B slot within a 128B row

  for (int k0 = 0; k0 < K; k0 += 64) {
#pragma unroll
    for (int i = 0; i < 4; ++i) {
      int rbase = (wid << 5) + (i << 3);
      int r = rbase + srow;
      int ca = schunk ^ (r & 7);  // inverse swizzle on the global source
      const ushort* ga = A  + (size_t)(t0 + r) * K + k0 + (ca << 3);
      __builtin_amdgcn_global_load_lds(
          (const __attribute__((address_space(1))) uint32_t*)ga,
          (__attribute__((address_space(3))) uint32_t*)(&At[rbase << 6]), 16, 0, 0);
      const ushort* gb = Bw + (size_t)(d0 + r) * K + k0 + (ca << 3);
      __builtin_amdgcn_global_load_lds(
          (const __attribute__((address_space(1))) uint32_t*)gb,
          (__attribute__((address_space(3))) uint32_t*)(&Bt[rbase << 6]), 16, 0, 0);
    }
    __syncthreads();

#pragma unroll
    for (int kk = 0; kk < 2; ++kk) {
      bf16x8 af[4], bfr[4];
      const int kc = (kk << 2) + (lane >> 4);
#pragma unroll
      for (int m = 0; m < 4; ++m) {
        int row = (wm << 6) + (m << 4) + (lane & 15);
        af[m]  = *(const bf16x8*)&At[(row << 6) + ((kc ^ (row & 7)) << 3)];
        int col = (wn << 6) + (m << 4) + (lane & 15);
        bfr[m] = *(const bf16x8*)&Bt[(col << 6) + ((kc ^ (col & 7)) << 3)];
      }
#pragma unroll
      for (int m = 0; m < 4; ++m)
#pragma unroll
        for (int n = 0; n < 4; ++n)
          acc[m][n] = __builtin_amdgcn_mfma_f32_16x16x32_bf16(af[m], bfr[n], acc[m][n], 0, 0, 0);
    }
    __syncthreads();
  }

  // epilogue: C/D layout col = lane&15, row = (lane>>4)*4 + reg
  float a0 = (EPI == 0) ? alpha[0] : 0.0f;
  float sA[4], s2A[4];
#pragma unroll
  for (int n = 0; n < 4; ++n) { sA[n] = 0.f; s2A[n] = 0.f; }

#pragma unroll
  for (int n = 0; n < 4; ++n) {
    int d = d0 + (wn << 6) + (n << 4) + (lane & 15);
    float bs = bias[d];
#pragma unroll
    for (int m = 0; m < 4; ++m) {
      int tb = t0 + (wm << 6) + (m << 4) + ((lane >> 4) << 2);
#pragma unroll
      for (int r = 0; r < 4; ++r) {
        float v = acc[m][n][r] + bs;
        if (EPI == 0) v = v > 0.f ? v : a0 * v;
        if (EPI == 1) { sA[n] += v; s2A[n] += v * v; }
        if (EPI == 2) {
          int row = tb + r;
          int orow = (row & ~255) | inv[row];
          ((float*)outp)[(size_t)orow * Dout + d] = v;
        } else {
          ((ushort*)outp)[(size_t)(tb + r) * Dout + d] = f2bf(v);
        }
      }
    }
  }

  if (EPI == 1) {
    // deterministic per-block column reduction (128 cols), then one slab row.
    float2* sm = (float2*)At;                   // 8 x 128 float2 = 8KB
    int slot = (wm << 2) | (lane >> 4);         // 0..7
#pragma unroll
    for (int n = 0; n < 4; ++n) {
      int col = (wn << 6) + (n << 4) + (lane & 15);
      sm[slot * 128 + col] = make_float2(sA[n], s2A[n]);
    }
    __syncthreads();
    if (tid < 128) {
      float ss = 0.f, ss2 = 0.f;
      for (int q = 0; q < 8; ++q) {
        float2 v = sm[q * 128 + tid];
        ss += v.x; ss2 += v.y;
      }
      part[(size_t)y * 2048 + d0 + tid]        = ss;
      part[(size_t)y * 2048 + 1024 + d0 + tid] = ss2;
    }
  }
}

// ------------------------------------------------------------ BN fold
__global__ void bnfold_kernel(const float* __restrict__ part, const float* __restrict__ g,
                              const float* __restrict__ bt, float* __restrict__ scsh) {
  int d = (blockIdx.x << 8) + threadIdx.x;    // grid 4
  float s = 0.f, s2 = 0.f;
  for (int j = 0; j < 256; ++j) { s += part[j * 2048 + d]; s2 += part[j * 2048 + 1024 + d]; }
  float mean = s * (1.f / 32768.f);
  float var  = s2 * (1.f / 32768.f) - mean * mean;
  float sc = g[d] * rsqrtf(var + 1e-5f);
  scsh[d] = sc;
  scsh[1024 + d] = bt[d] - mean * sc;
}

// y = prelu(y*sc + sh, p) [+ pos, prelu am], in place, 8 bf16/thread
template<bool MIX>
__global__ void bnact_kernel(ushort* __restrict__ Y, const float* __restrict__ scsh,
                             const float* __restrict__ p, const float* __restrict__ pos,
                             const float* __restrict__ am) {
  size_t i = (((size_t)blockIdx.x << 8) + threadIdx.x) << 3;
  int d = (int)(i & 1023);
  float pp = p[0];
  float aa = MIX ? am[0] : 0.f;
  float pv[8];
  if (MIX) {
    int prow = (int)((i >> 10) & 255);
    const float4* pb = (const float4*)(pos + ((size_t)prow << 10) + d);
    float4 pA = pb[0], pB = pb[1];
    pv[0]=pA.x; pv[1]=pA.y; pv[2]=pA.z; pv[3]=pA.w;
    pv[4]=pB.x; pv[5]=pB.y; pv[6]=pB.z; pv[7]=pB.w;
  }
  uint4 raw = *(const uint4*)(Y + i);
  uint32_t w[4] = {raw.x, raw.y, raw.z, raw.w};
  uint32_t o[4];
#pragma unroll
  for (int q = 0; q < 4; ++q) {
    int dd = d + q * 2;
    float v0 = bf2f(w[q] & 0xFFFFu) * scsh[dd]     + scsh[1024 + dd];
    float v1 = bf2f(w[q] >> 16)     * scsh[dd + 1] + scsh[1024 + dd + 1];
    v0 = v0 > 0.f ? v0 : pp * v0;
    v1 = v1 > 0.f ? v1 : pp * v1;
    if (MIX) {
      v0 += pv[2 * q];     v1 += pv[2 * q + 1];
      v0 = v0 > 0.f ? v0 : aa * v0;
      v1 = v1 > 0.f ? v1 : aa * v1;
    }
    o[q] = (uint32_t)f2bf(v0) | ((uint32_t)f2bf(v1) << 16);
  }
  *(uint4*)(Y + i) = make_uint4(o[0], o[1], o[2], o[3]);
}

// inverse permutation: inv[b, perm[b,i]] = i
__global__ void invperm_kernel(const int* __restrict__ perm, int* __restrict__ inv) {
  int t = (blockIdx.x << 8) + threadIdx.x;    // 32768
  inv[(t & ~255) + perm[t]] = t & 255;
}

// ----------------------------------------------------------- preprocessing
__global__ void f2b_kernel(const float* __restrict__ in, ushort* __restrict__ out, int n) {
  int i = (blockIdx.x << 8) + threadIdx.x;
  if (i < n) out[i] = f2bf(in[i]);
}

__global__ void padw0_kernel(const float* __restrict__ w0, ushort* __restrict__ o) {
  int d = blockIdx.x, j = threadIdx.x;  // 1024 x 192
  o[d * 192 + j] = (j < 147) ? f2bf(w0[d * 147 + j]) : (ushort)0;
}

// patch im2col: P[t=b*256+pi*16+pj][j=cin*49+dy*7+dx] = x[b,cin,7pi+dy,7pj+dx]
__global__ void im2col_kernel(const float* __restrict__ x, ushort* __restrict__ P) {
  int t = blockIdx.x;        // 32768
  int j = threadIdx.x;       // 192
  ushort v = 0;
  if (j < 147) {
    int b = t >> 8, pidx = t & 255;
    int pi = pidx >> 4, pj = pidx & 15;
    int cin = j / 49, rem = j - cin * 49;
    int dy = rem / 7, dx = rem - dy * 7;
    v = f2bf(x[(size_t)(b * 3 + cin) * 12544 + (size_t)(pi * 7 + dy) * 112 + (pj * 7 + dx)]);
  }
  P[(size_t)t * 192 + j] = v;
}

extern "C" void kernel_launch(void* const* d_in, const int* in_sizes, int n_in,
                              void* d_out, int out_size, void* d_ws, size_t ws_size,
                              hipStream_t stream) {
  const float* x   = (const float*)d_in[0];
  const float* w0  = (const float*)d_in[1];
  const float* b0  = (const float*)d_in[2];
  const float* a0  = (const float*)d_in[3];
  const float* w1  = (const float*)d_in[4];
  const float* b1  = (const float*)d_in[5];
  const float* g1  = (const float*)d_in[6];
  const float* bt1 = (const float*)d_in[7];
  const float* p1  = (const float*)d_in[8];
  const float* w2  = (const float*)d_in[9];
  const float* b2  = (const float*)d_in[10];
  const float* g2  = (const float*)d_in[11];
  const float* bt2 = (const float*)d_in[12];
  const float* p2  = (const float*)d_in[13];
  const float* w3  = (const float*)d_in[14];
  const float* b3  = (const float*)d_in[15];
  const float* g3  = (const float*)d_in[16];
  const float* bt3 = (const float*)d_in[17];
  const float* p3  = (const float*)d_in[18];
  const float* pos = (const float*)d_in[19];
  const float* am  = (const float*)d_in[20];
  const float* wm  = (const float*)d_in[21];
  const float* bm  = (const float*)d_in[22];
  const int*  perm = (const int*)d_in[23];

  char* ws = (char*)d_ws;
  ushort* B0   = (ushort*)ws;                                   // 64MB
  ushort* B1   = (ushort*)(ws + 67108864);                      // 64MB
  float*  part = (float*)(ws + 134217728);                      // 256*2048*4 = 2MB
  float*  scsh = (float*)(ws + 134217728 + 2097152);            // 8KB
  int*    inv  = (int*)  (ws + 134217728 + 2097152 + 8192);     // 128KB
  ushort* wbuf = (ushort*)(ws + 134217728 + 2097152 + 8192 + 131072); // 2MB

  invperm_kernel<<<dim3(128), dim3(256), 0, stream>>>(perm, inv);
  im2col_kernel<<<dim3(32768), dim3(192), 0, stream>>>(x, B1);
  padw0_kernel<<<dim3(1024), dim3(192), 0, stream>>>(w0, wbuf);

  // patch-embed conv as GEMM: P(B1) x w0^T -> act0(B0), bias+prelu
  gemm_kernel<0, 3><<<dim3(2048), dim3(256), 0, stream>>>(
      B1, wbuf, b0, a0, (void*)B0, nullptr, nullptr, 192, 1024);

  // layer 1: B0 -> B1  (stats fused)
  f2b_kernel<<<dim3(4096), dim3(256), 0, stream>>>(w1, wbuf, 1048576);
  gemm_kernel<1, 3><<<dim3(2048), dim3(256), 0, stream>>>(
      B0, wbuf, b1, nullptr, (void*)B1, part, nullptr, 1024, 1024);
  bnfold_kernel<<<dim3(4), dim3(256), 0, stream>>>(part, g1, bt1, scsh);
  bnact_kernel<false><<<dim3(16384), dim3(256), 0, stream>>>(B1, scsh, p1, nullptr, nullptr);

  // layer 2: B1 -> B0
  f2b_kernel<<<dim3(4096), dim3(256), 0, stream>>>(w2, wbuf, 1048576);
  gemm_kernel<1, 3><<<dim3(2048), dim3(256), 0, stream>>>(
      B1, wbuf, b2, nullptr, (void*)B0, part, nullptr, 1024, 1024);
  bnfold_kernel<<<dim3(4), dim3(256), 0, stream>>>(part, g2, bt2, scsh);
  bnact_kernel<false><<<dim3(16384), dim3(256), 0, stream>>>(B0, scsh, p2, nullptr, nullptr);

  // layer 3: B0 -> B1, bnact fused with +pos & prelu(am)
  f2b_kernel<<<dim3(4096), dim3(256), 0, stream>>>(w3, wbuf, 1048576);
  gemm_kernel<1, 3><<<dim3(2048), dim3(256), 0, stream>>>(
      B0, wbuf, b3, nullptr, (void*)B1, part, nullptr, 1024, 1024);
  bnfold_kernel<<<dim3(4), dim3(256), 0, stream>>>(part, g3, bt3, scsh);
  bnact_kernel<true><<<dim3(16384), dim3(256), 0, stream>>>(B1, scsh, p3, pos, am);

  // mixer: out = (enc @ wm^T + bm) rows scattered via inv -> d_out (fp32)
  f2b_kernel<<<dim3(2048), dim3(256), 0, stream>>>(wm, wbuf, 524288);
  gemm_kernel<2, 2><<<dim3(1024), dim3(256), 0, stream>>>(
      B1, wbuf, bm, nullptr, d_out, nullptr, inv, 1024, 512);
}

// Round 3
// 457.221 us; speedup vs baseline: 1.2794x; 1.0707x over previous
//
#include <hip/hip_runtime.h>
#include <hip/hip_bf16.h>
#include <stdint.h>

// Encoder pipeline, activations token-major [T=32768, C] bf16.
// im2col -> convGEMM(+b0,prelu) -> 3x { GEMM(+b, fused col-stats) -> bnfold ->
// bnact(prelu[, +pos,prelu am on layer3]) } -> mixGEMM(+bm, fp32, fused perm-scatter)
// GEMM: 128x128 tile, BK=64, counted-vmcnt double-buffered pipeline:
//   window t: vmcnt(8); barrier; reads+MFMA(setprio); lgkmcnt(0); barrier; stage(t+2)->buf[t&1]
// Stage into a buffer is issued only after the barrier that ends all reads of it -> race-free.
// ws: B0(64MB) | B1(64MB) | part(2MB) | scsh(8KB) | inv(128KB) | wbuf(2MB)

typedef __attribute__((ext_vector_type(8))) short bf16x8;
typedef __attribute__((ext_vector_type(4))) float f32x4;

__device__ __forceinline__ float bf2f(uint32_t u) {
  union { uint32_t i; float f; } v; v.i = u << 16; return v.f;
}
__device__ __forceinline__ ushort f2bf(float f) {
  union { float f; uint32_t i; } v; v.f = f;
  uint32_t i = v.i;
  return (ushort)((i + 0x7FFFu + ((i >> 16) & 1u)) >> 16);
}

// ---------------------------------------------------------------- GEMM
// Out[t,d] = sum_k A[t,k] * Bw[d,k]  (bf16, K-contiguous), fp32 accum.
// 4 waves (2x2 of 64x64), mfma_f32_16x16x32_bf16.
// LDS [2][128][64] K-major per operand, XOR chunk swizzle (slot = chunk ^ (row&7));
// staged via global_load_lds with inverse-swizzled global source.
// 1-D grid with XCD-grouping swizzle (8 d-blocks sharing an A-tile run on one XCD).
// EPI: 0 = bias+prelu -> bf16
//      1 = bias -> bf16, + per-y-slab column sum/sumsq partials into `part`
//      2 = bias -> fp32, rows scattered via inverse permutation (mixer)
template<int EPI, int XB>
__global__ void __launch_bounds__(256, 2)
gemm_kernel(const ushort* __restrict__ A, const ushort* __restrict__ Bw,
            const float* __restrict__ bias, const float* __restrict__ alpha,
            void* __restrict__ outp, float* __restrict__ part,
            const int* __restrict__ inv, int K, int Dout)
{
  __shared__ __align__(16) ushort At[2][128 * 64];
  __shared__ __align__(16) ushort Bt[2][128 * 64];
  const int tid  = threadIdx.x;
  const int lane = tid & 63;
  const int wid  = tid >> 6;
  const int wm = wid >> 1, wn = wid & 1;

  // XCD-grouping swizzle: s = ((y>>3)*NX + x)*8 + (y&7)
  const int s = blockIdx.x;
  const int j = s >> 3;
  const int x = j & ((1 << XB) - 1);
  const int y = ((j >> XB) << 3) | (s & 7);
  const int t0 = y << 7;
  const int d0 = x << 7;

  f32x4 acc[4][4] = {};

  const int srow   = lane >> 3;   // row within an 8-row staging group
  const int schunk = lane & 7;    // 16B slot within a 128B row
  const int NT = K >> 6;

  auto stage = [&](int t, int buf) {
    const int k0 = t << 6;
#pragma unroll
    for (int i = 0; i < 4; ++i) {
      int rbase = (wid << 5) + (i << 3);
      int r = rbase + srow;
      int ca = schunk ^ (r & 7);  // inverse swizzle on the global source
      const ushort* ga = A  + (size_t)(t0 + r) * K + k0 + (ca << 3);
      __builtin_amdgcn_global_load_lds(
          (const __attribute__((address_space(1))) uint32_t*)ga,
          (__attribute__((address_space(3))) uint32_t*)(&At[buf][rbase << 6]), 16, 0, 0);
      const ushort* gb = Bw + (size_t)(d0 + r) * K + k0 + (ca << 3);
      __builtin_amdgcn_global_load_lds(
          (const __attribute__((address_space(1))) uint32_t*)gb,
          (__attribute__((address_space(3))) uint32_t*)(&Bt[buf][rbase << 6]), 16, 0, 0);
    }
  };

  stage(0, 0);
  if (NT > 1) stage(1, 1);

  for (int t = 0; t < NT; ++t) {
    const int cur = t & 1;
    // tile t landed (my 8 stage loads of t+1 may stay in flight)
    if (t + 1 < NT) { asm volatile("s_waitcnt vmcnt(8)" ::: "memory"); }
    else            { asm volatile("s_waitcnt vmcnt(0)" ::: "memory"); }
    __builtin_amdgcn_s_barrier();    // everyone's tile-t loads landed

    __builtin_amdgcn_s_setprio(1);
#pragma unroll
    for (int kk = 0; kk < 2; ++kk) {
      bf16x8 af[4], bfr[4];
      const int kc = (kk << 2) + (lane >> 4);
#pragma unroll
      for (int m = 0; m < 4; ++m) {
        int row = (wm << 6) + (m << 4) + (lane & 15);
        af[m]  = *(const bf16x8*)&At[cur][(row << 6) + ((kc ^ (row & 7)) << 3)];
        int col = (wn << 6) + (m << 4) + (lane & 15);
        bfr[m] = *(const bf16x8*)&Bt[cur][(col << 6) + ((kc ^ (col & 7)) << 3)];
      }
#pragma unroll
      for (int m = 0; m < 4; ++m)
#pragma unroll
        for (int n = 0; n < 4; ++n)
          acc[m][n] = __builtin_amdgcn_mfma_f32_16x16x32_bf16(af[m], bfr[n], acc[m][n], 0, 0, 0);
    }
    __builtin_amdgcn_s_setprio(0);
    asm volatile("s_waitcnt lgkmcnt(0)" ::: "memory");   // all my reads of buf[cur] done
    __builtin_amdgcn_s_barrier();                        // ... and everyone else's
    asm volatile("" ::: "memory");
    if (t + 2 < NT) stage(t + 2, cur);                   // safe: no reader of buf[cur] until
  }                                                      // the vmcnt+barrier gate at window t+2

  // epilogue: C/D layout col = lane&15, row = (lane>>4)*4 + reg
  float a0 = (EPI == 0) ? alpha[0] : 0.0f;
  float sA[4], s2A[4];
#pragma unroll
  for (int n = 0; n < 4; ++n) { sA[n] = 0.f; s2A[n] = 0.f; }

#pragma unroll
  for (int n = 0; n < 4; ++n) {
    int d = d0 + (wn << 6) + (n << 4) + (lane & 15);
    float bs = bias[d];
#pragma unroll
    for (int m = 0; m < 4; ++m) {
      int tb = t0 + (wm << 6) + (m << 4) + ((lane >> 4) << 2);
#pragma unroll
      for (int r = 0; r < 4; ++r) {
        float v = acc[m][n][r] + bs;
        if (EPI == 0) v = v > 0.f ? v : a0 * v;
        if (EPI == 1) { sA[n] += v; s2A[n] += v * v; }
        if (EPI == 2) {
          int row = tb + r;
          int orow = (row & ~255) | inv[row];
          ((float*)outp)[(size_t)orow * Dout + d] = v;
        } else {
          ((ushort*)outp)[(size_t)(tb + r) * Dout + d] = f2bf(v);
        }
      }
    }
  }

  if (EPI == 1) {
    // deterministic per-block column reduction (128 cols), then one slab row.
    float2* sm = (float2*)&At[0][0];            // 8 x 128 float2 = 8KB
    int slot = (wm << 2) | (lane >> 4);         // 0..7
#pragma unroll
    for (int n = 0; n < 4; ++n) {
      int col = (wn << 6) + (n << 4) + (lane & 15);
      sm[slot * 128 + col] = make_float2(sA[n], s2A[n]);
    }
    __syncthreads();
    if (tid < 128) {
      float ss = 0.f, ss2 = 0.f;
      for (int q = 0; q < 8; ++q) {
        float2 v = sm[q * 128 + tid];
        ss += v.x; ss2 += v.y;
      }
      part[(size_t)y * 2048 + d0 + tid]        = ss;
      part[(size_t)y * 2048 + 1024 + d0 + tid] = ss2;
    }
  }
}

// ------------------------------------------------------------ BN fold
__global__ void bnfold_kernel(const float* __restrict__ part, const float* __restrict__ g,
                              const float* __restrict__ bt, float* __restrict__ scsh) {
  int d = (blockIdx.x << 8) + threadIdx.x;    // grid 4
  float s = 0.f, s2 = 0.f;
  for (int j = 0; j < 256; ++j) { s += part[j * 2048 + d]; s2 += part[j * 2048 + 1024 + d]; }
  float mean = s * (1.f / 32768.f);
  float var  = s2 * (1.f / 32768.f) - mean * mean;
  float sc = g[d] * rsqrtf(var + 1e-5f);
  scsh[d] = sc;
  scsh[1024 + d] = bt[d] - mean * sc;
}

// y = prelu(y*sc + sh, p) [+ pos, prelu am], in place, 8 bf16/thread
template<bool MIX>
__global__ void bnact_kernel(ushort* __restrict__ Y, const float* __restrict__ scsh,
                             const float* __restrict__ p, const float* __restrict__ pos,
                             const float* __restrict__ am) {
  size_t i = (((size_t)blockIdx.x << 8) + threadIdx.x) << 3;
  int d = (int)(i & 1023);
  float pp = p[0];
  float aa = MIX ? am[0] : 0.f;
  float pv[8];
  if (MIX) {
    int prow = (int)((i >> 10) & 255);
    const float4* pb = (const float4*)(pos + ((size_t)prow << 10) + d);
    float4 pA = pb[0], pB = pb[1];
    pv[0]=pA.x; pv[1]=pA.y; pv[2]=pA.z; pv[3]=pA.w;
    pv[4]=pB.x; pv[5]=pB.y; pv[6]=pB.z; pv[7]=pB.w;
  }
  uint4 raw = *(const uint4*)(Y + i);
  uint32_t w[4] = {raw.x, raw.y, raw.z, raw.w};
  uint32_t o[4];
#pragma unroll
  for (int q = 0; q < 4; ++q) {
    int dd = d + q * 2;
    float v0 = bf2f(w[q] & 0xFFFFu) * scsh[dd]     + scsh[1024 + dd];
    float v1 = bf2f(w[q] >> 16)     * scsh[dd + 1] + scsh[1024 + dd + 1];
    v0 = v0 > 0.f ? v0 : pp * v0;
    v1 = v1 > 0.f ? v1 : pp * v1;
    if (MIX) {
      v0 += pv[2 * q];     v1 += pv[2 * q + 1];
      v0 = v0 > 0.f ? v0 : aa * v0;
      v1 = v1 > 0.f ? v1 : aa * v1;
    }
    o[q] = (uint32_t)f2bf(v0) | ((uint32_t)f2bf(v1) << 16);
  }
  *(uint4*)(Y + i) = make_uint4(o[0], o[1], o[2], o[3]);
}

// inverse permutation: inv[b, perm[b,i]] = i
__global__ void invperm_kernel(const int* __restrict__ perm, int* __restrict__ inv) {
  int t = (blockIdx.x << 8) + threadIdx.x;    // 32768
  inv[(t & ~255) + perm[t]] = t & 255;
}

// ----------------------------------------------------------- preprocessing
__global__ void f2b_kernel(const float* __restrict__ in, ushort* __restrict__ out, int n) {
  int i = (blockIdx.x << 8) + threadIdx.x;
  if (i < n) out[i] = f2bf(in[i]);
}

__global__ void padw0_kernel(const float* __restrict__ w0, ushort* __restrict__ o) {
  int d = blockIdx.x, j = threadIdx.x;  // 1024 x 192
  o[d * 192 + j] = (j < 147) ? f2bf(w0[d * 147 + j]) : (ushort)0;
}

// patch im2col: P[t=b*256+pi*16+pj][j=cin*49+dy*7+dx] = x[b,cin,7pi+dy,7pj+dx]
__global__ void im2col_kernel(const float* __restrict__ x, ushort* __restrict__ P) {
  int t = blockIdx.x;        // 32768
  int j = threadIdx.x;       // 192
  ushort v = 0;
  if (j < 147) {
    int b = t >> 8, pidx = t & 255;
    int pi = pidx >> 4, pj = pidx & 15;
    int cin = j / 49, rem = j - cin * 49;
    int dy = rem / 7, dx = rem - dy * 7;
    v = f2bf(x[(size_t)(b * 3 + cin) * 12544 + (size_t)(pi * 7 + dy) * 112 + (pj * 7 + dx)]);
  }
  P[(size_t)t * 192 + j] = v;
}

extern "C" void kernel_launch(void* const* d_in, const int* in_sizes, int n_in,
                              void* d_out, int out_size, void* d_ws, size_t ws_size,
                              hipStream_t stream) {
  const float* x   = (const float*)d_in[0];
  const float* w0  = (const float*)d_in[1];
  const float* b0  = (const float*)d_in[2];
  const float* a0  = (const float*)d_in[3];
  const float* w1  = (const float*)d_in[4];
  const float* b1  = (const float*)d_in[5];
  const float* g1  = (const float*)d_in[6];
  const float* bt1 = (const float*)d_in[7];
  const float* p1  = (const float*)d_in[8];
  const float* w2  = (const float*)d_in[9];
  const float* b2  = (const float*)d_in[10];
  const float* g2  = (const float*)d_in[11];
  const float* bt2 = (const float*)d_in[12];
  const float* p2  = (const float*)d_in[13];
  const float* w3  = (const float*)d_in[14];
  const float* b3  = (const float*)d_in[15];
  const float* g3  = (const float*)d_in[16];
  const float* bt3 = (const float*)d_in[17];
  const float* p3  = (const float*)d_in[18];
  const float* pos = (const float*)d_in[19];
  const float* am  = (const float*)d_in[20];
  const float* wm  = (const float*)d_in[21];
  const float* bm  = (const float*)d_in[22];
  const int*  perm = (const int*)d_in[23];

  char* ws = (char*)d_ws;
  ushort* B0   = (ushort*)ws;                                   // 64MB
  ushort* B1   = (ushort*)(ws + 67108864);                      // 64MB
  float*  part = (float*)(ws + 134217728);                      // 256*2048*4 = 2MB
  float*  scsh = (float*)(ws + 134217728 + 2097152);            // 8KB
  int*    inv  = (int*)  (ws + 134217728 + 2097152 + 8192);     // 128KB
  ushort* wbuf = (ushort*)(ws + 134217728 + 2097152 + 8192 + 131072); // 2MB

  invperm_kernel<<<dim3(128), dim3(256), 0, stream>>>(perm, inv);
  im2col_kernel<<<dim3(32768), dim3(192), 0, stream>>>(x, B1);
  padw0_kernel<<<dim3(1024), dim3(192), 0, stream>>>(w0, wbuf);

  // patch-embed conv as GEMM: P(B1) x w0^T -> act0(B0), bias+prelu
  gemm_kernel<0, 3><<<dim3(2048), dim3(256), 0, stream>>>(
      B1, wbuf, b0, a0, (void*)B0, nullptr, nullptr, 192, 1024);

  // layer 1: B0 -> B1  (stats fused)
  f2b_kernel<<<dim3(4096), dim3(256), 0, stream>>>(w1, wbuf, 1048576);
  gemm_kernel<1, 3><<<dim3(2048), dim3(256), 0, stream>>>(
      B0, wbuf, b1, nullptr, (void*)B1, part, nullptr, 1024, 1024);
  bnfold_kernel<<<dim3(4), dim3(256), 0, stream>>>(part, g1, bt1, scsh);
  bnact_kernel<false><<<dim3(16384), dim3(256), 0, stream>>>(B1, scsh, p1, nullptr, nullptr);

  // layer 2: B1 -> B0
  f2b_kernel<<<dim3(4096), dim3(256), 0, stream>>>(w2, wbuf, 1048576);
  gemm_kernel<1, 3><<<dim3(2048), dim3(256), 0, stream>>>(
      B1, wbuf, b2, nullptr, (void*)B0, part, nullptr, 1024, 1024);
  bnfold_kernel<<<dim3(4), dim3(256), 0, stream>>>(part, g2, bt2, scsh);
  bnact_kernel<false><<<dim3(16384), dim3(256), 0, stream>>>(B0, scsh, p2, nullptr, nullptr);

  // layer 3: B0 -> B1, bnact fused with +pos & prelu(am)
  f2b_kernel<<<dim3(4096), dim3(256), 0, stream>>>(w3, wbuf, 1048576);
  gemm_kernel<1, 3><<<dim3(2048), dim3(256), 0, stream>>>(
      B0, wbuf, b3, nullptr, (void*)B1, part, nullptr, 1024, 1024);
  bnfold_kernel<<<dim3(4), dim3(256), 0, stream>>>(part, g3, bt3, scsh);
  bnact_kernel<true><<<dim3(16384), dim3(256), 0, stream>>>(B1, scsh, p3, pos, am);

  // mixer: out = (enc @ wm^T + bm) rows scattered via inv -> d_out (fp32)
  f2b_kernel<<<dim3(2048), dim3(256), 0, stream>>>(wm, wbuf, 524288);
  gemm_kernel<2, 2><<<dim3(1024), dim3(256), 0, stream>>>(
      B1, wbuf, bm, nullptr, d_out, nullptr, inv, 1024, 512);
}